// Round 7
// baseline (5486.830 us; speedup 1.0000x reference)
//
#include <hip/hip_runtime.h>

#define DIM 2048
#define LEAK 0.2f

typedef __bf16 bf16x8 __attribute__((ext_vector_type(8)));
typedef float  f32x4  __attribute__((ext_vector_type(4)));
typedef unsigned int u32x4 __attribute__((ext_vector_type(4)));
typedef int    i32x4  __attribute__((ext_vector_type(4)));

static __device__ __forceinline__ unsigned short f2bf(float f) {
    unsigned int x = __float_as_uint(f);
    return (unsigned short)((x + 0x7fffu + ((x >> 16) & 1u)) >> 16);  // RNE
}
static __device__ __forceinline__ float bf2f(unsigned short h) {
    return __uint_as_float(((unsigned int)h) << 16);
}

static __device__ __forceinline__ void async16(const void* g, void* s) {
    __builtin_amdgcn_global_load_lds(
        (const __attribute__((address_space(1))) void*)g,
        (__attribute__((address_space(3))) void*)s, 16, 0, 0);
}

static __device__ __forceinline__ bf16x8 ld_bf16_frag(const char* p) {
    union { u32x4 u; bf16x8 v; } cv;
    cv.u = *(const u32x4*)p;   // ds_read_b128
    return cv.v;
}

// ---------------- prep kernels ----------------

__global__ __launch_bounds__(256) void split_kernel(
    const float* __restrict__ in,
    unsigned short* __restrict__ hi, unsigned short* __restrict__ lo) {
    int idx = blockIdx.x * 256 + threadIdx.x;
    float4 v = ((const float4*)in)[idx];
    ushort4 h, l;
    h.x = f2bf(v.x); l.x = f2bf(v.x - bf2f(h.x));
    h.y = f2bf(v.y); l.y = f2bf(v.y - bf2f(h.y));
    h.z = f2bf(v.z); l.z = f2bf(v.z - bf2f(h.z));
    h.w = f2bf(v.w); l.w = f2bf(v.w - bf2f(h.w));
    ((ushort4*)hi)[idx] = h;
    ((ushort4*)lo)[idx] = l;
}

__global__ __launch_bounds__(256) void transpose_split(
    const float* __restrict__ in,
    unsigned short* __restrict__ hiT, unsigned short* __restrict__ loT) {
    __shared__ float t[32][33];
    int bx = blockIdx.x, by = blockIdx.y;
    int tx = threadIdx.x & 31, ty4 = (threadIdx.x >> 5) << 2;
#pragma unroll
    for (int i = 0; i < 4; i++)
        t[ty4 + i][tx] = in[(size_t)(by * 32 + ty4 + i) * DIM + bx * 32 + tx];
    __syncthreads();
#pragma unroll
    for (int i = 0; i < 4; i++) {
        float v = t[tx][ty4 + i];
        size_t o = (size_t)(bx * 32 + ty4 + i) * DIM + by * 32 + tx;
        unsigned short h = f2bf(v);
        hiT[o] = h;
        loT[o] = f2bf(v - bf2f(h));
    }
}

__global__ __launch_bounds__(256) void transpose_i8(
    const float* __restrict__ in, signed char* __restrict__ outT) {
    __shared__ float t[32][33];
    int bx = blockIdx.x, by = blockIdx.y;
    int tx = threadIdx.x & 31, ty4 = (threadIdx.x >> 5) << 2;
#pragma unroll
    for (int i = 0; i < 4; i++)
        t[ty4 + i][tx] = in[(size_t)(by * 32 + ty4 + i) * DIM + bx * 32 + tx];
    __syncthreads();
#pragma unroll
    for (int i = 0; i < 4; i++)
        outT[(size_t)(bx * 32 + ty4 + i) * DIM + by * 32 + tx] =
            (signed char)t[tx][ty4 + i];
}

__global__ __launch_bounds__(256) void quant_split(
    const float* __restrict__ in,
    signed char* __restrict__ hi, signed char* __restrict__ lo) {
    int idx = blockIdx.x * 256 + threadIdx.x;
    float4 v = ((const float4*)in)[idx];
    char4 h, l;
    {
        int q = (int)rintf(v.x * 16384.f); q = q > 16383 ? 16383 : (q < -16383 ? -16383 : q);
        h.x = (signed char)(q >> 7); l.x = (signed char)(q & 127);
    }
    {
        int q = (int)rintf(v.y * 16384.f); q = q > 16383 ? 16383 : (q < -16383 ? -16383 : q);
        h.y = (signed char)(q >> 7); l.y = (signed char)(q & 127);
    }
    {
        int q = (int)rintf(v.z * 16384.f); q = q > 16383 ? 16383 : (q < -16383 ? -16383 : q);
        h.z = (signed char)(q >> 7); l.z = (signed char)(q & 127);
    }
    {
        int q = (int)rintf(v.w * 16384.f); q = q > 16383 ? 16383 : (q < -16383 ? -16383 : q);
        h.w = (signed char)(q >> 7); l.w = (signed char)(q & 127);
    }
    ((char4*)hi)[idx] = h;
    ((char4*)lo)[idx] = l;
}

// ---------------- bf16 dual-A GEMM (drive), tile 64x128, dbuf ----------------
// MODE 0: Cout = (Ahi+Alo) @ B^T        MODE 1: Cout = Cin + P + bias[n]
// (proven round-0 kernel, 2x44us)
template <int MODE>
__global__ __launch_bounds__(256) void gemm_bf16(
    const unsigned short* __restrict__ Ahi,
    const unsigned short* __restrict__ Alo,
    const unsigned short* __restrict__ BT,
    const float* __restrict__ Cin,
    const float* __restrict__ bias,
    float* __restrict__ Cout) {
    __shared__ alignas(16) char sA[2][16384];
    __shared__ alignas(16) char sB[2][16384];

    const int bid = blockIdx.x;
    const int xcd = bid & 7, slot = bid >> 3;
    const int tm = ((xcd >> 1) << 3) + (slot >> 3);      // 0..31
    const int tn = ((xcd & 1) << 3) + (slot & 7);        // 0..15
    const int row0 = tm << 6, col0 = tn << 7;

    const int tid = threadIdx.x;
    const int lane = tid & 63;
    const int quad = lane >> 4, l16 = lane & 15;
    const int wave = tid >> 6;
    const int wm = wave >> 1, wn = wave & 1;

    const unsigned short* a_src[4]; int a_dst[4];
    const unsigned short* b_src[4]; int b_dst[4];
#pragma unroll
    for (int i = 0; i < 4; i++) {
        int s = tid + 256 * i;                 // 0..1023
        {
            int r = s >> 4, g = (s >> 3) & 1, c = (s & 7) ^ (r & 7);
            a_src[i] = (g ? Alo : Ahi) + (size_t)(row0 + r) * DIM + c * 8;
            a_dst[i] = s * 16;
        }
        {
            int r = s >> 3, c = (s & 7) ^ (r & 7);
            b_src[i] = BT + (size_t)(col0 + r) * DIM + c * 8;
            b_dst[i] = s * 16;
        }
    }

    f32x4 acc[2][4] = {};

    auto stage = [&](int p, int k0) {
#pragma unroll
        for (int i = 0; i < 4; i++) {
            async16(a_src[i] + k0, sA[p] + a_dst[i]);
            async16(b_src[i] + k0, sB[p] + b_dst[i]);
        }
    };

    stage(0, 0);
    __syncthreads();
    for (int it = 0; it < 32; it++) {          // BK = 64 elems (128B)
        const int p = it & 1;
        if (it + 1 < 32) stage(1 - p, (it + 1) * 64);
#pragma unroll
        for (int kk = 0; kk < 2; kk++) {       // two K=32 MFMA phases
            bf16x8 ah[2], al[2], bv[4];
#pragma unroll
            for (int i = 0; i < 2; i++) {
                const int r = (wm << 5) + (i << 4) + l16;
                const int cs = ((kk << 2) + quad) ^ (r & 7);
                ah[i] = ld_bf16_frag(sA[p] + ((r << 4) + cs) * 16);
                al[i] = ld_bf16_frag(sA[p] + ((r << 4) + 8 + cs) * 16);
            }
#pragma unroll
            for (int j = 0; j < 4; j++) {
                const int r = (wn << 6) + (j << 4) + l16;
                const int cs = ((kk << 2) + quad) ^ (r & 7);
                bv[j] = ld_bf16_frag(sB[p] + ((r << 3) + cs) * 16);
            }
#pragma unroll
            for (int i = 0; i < 2; i++)
#pragma unroll
                for (int j = 0; j < 4; j++) {
                    acc[i][j] = __builtin_amdgcn_mfma_f32_16x16x32_bf16(ah[i], bv[j], acc[i][j], 0, 0, 0);
                    acc[i][j] = __builtin_amdgcn_mfma_f32_16x16x32_bf16(al[i], bv[j], acc[i][j], 0, 0, 0);
                }
        }
        __syncthreads();
    }

#pragma unroll
    for (int i = 0; i < 2; i++) {
        const int rb = row0 + (wm << 5) + (i << 4) + (quad << 2);
#pragma unroll
        for (int j = 0; j < 4; j++) {
            const int c = col0 + (wn << 6) + (j << 4) + l16;
#pragma unroll
            for (int g = 0; g < 4; g++) {
                const size_t idx = (size_t)(rb + g) * DIM + c;
                if (MODE == 0) Cout[idx] = acc[i][j][g];
                else           Cout[idx] = Cin[idx] + acc[i][j][g] + bias[c];
            }
        }
    }
}

// ---------------- persistent recurrence via software global barrier ----------
// Plain launch (no cooperative API -- r3's hipLaunchCooperativeKernel silently
// no-op'd under this harness).  Grid 512 x 256thr, LDS 64KB/block,
// __launch_bounds__(256,2) (VGPR<=256): 2 blocks/CU strictly co-resident ->
// all 512 blocks resident -> spin barrier cannot deadlock.
// Barrier: monotonic-generation counter (no reset races; 64*512 << 2^31) with
// device-scope atomics; __threadfence() release/acquire (buffer_wbl2 /
// buffer_inv) handles cross-XCD L2 non-coherence.  Self-cleaning: the 512th
// finisher zeroes the counters, so repeated harness launches start clean.
// Per-step K-loop and all addressing are byte-identical to the proven round-0
// step_i8.  Persistent wins: drive (16MB/step) + sold decode (8MB/step) live
// in 64 resident VGPRs; next-step B (state-independent) pre-staged before the
// barrier; zero inter-step launch gaps.
__device__ unsigned g_barcnt = 0u;
__device__ unsigned g_barflag = 0u;
__device__ unsigned g_done = 0u;

__global__ __launch_bounds__(256, 2) void step_persist(
    signed char* __restrict__ h1, signed char* __restrict__ l1,
    signed char* __restrict__ h2, signed char* __restrict__ l2,
    const signed char* __restrict__ BT,
    const float* __restrict__ drive,
    const float* __restrict__ st0,
    float* __restrict__ out) {
    __shared__ alignas(16) char sA[2][16384];  // 64 rows x 256B (hi 0-7 | lo 8-15), swizzled
    __shared__ alignas(16) char sB[2][16384];  // 128 rows x 128B, swizzled

    const int bid = blockIdx.x;
    const int xcd = bid & 7, slot = bid >> 3;
    const int tm = ((xcd >> 1) << 3) + (slot >> 3);      // 0..31
    const int tn = ((xcd & 1) << 3) + (slot & 7);        // 0..15
    const int row0 = tm << 6, col0 = tn << 7;

    const int tid = threadIdx.x;
    const int lane = tid & 63;
    const int quad = lane >> 4, l16 = lane & 15;
    const int wave = tid >> 6;
    const int wm = wave >> 1, wn = wave & 1;

    // staging addresses: A as plane-relative offsets (base ping-pongs), B fixed
    size_t a_off[4]; int a_dst[4]; int a_lo[4];
    const signed char* b_src[4]; int b_dst[4];
#pragma unroll
    for (int i = 0; i < 4; i++) {
        int s = tid + 256 * i;                 // 0..1023
        {
            int r = s >> 4, g = (s >> 3) & 1, c = (s & 7) ^ (r & 7);
            a_lo[i] = g;
            a_off[i] = (size_t)(row0 + r) * DIM + c * 16;
            a_dst[i] = s * 16;
        }
        {
            int r = s >> 3, c = (s & 7) ^ (r & 7);
            b_src[i] = BT + (size_t)(col0 + r) * DIM + c * 16;
            b_dst[i] = s * 16;
        }
    }

    // resident registers: drive tile + f32 state tile (layout = epilogue layout)
    float dreg[2][4][4], sreg[2][4][4];
#pragma unroll
    for (int i = 0; i < 2; i++) {
        const int rb = row0 + (wm << 5) + (i << 4) + (quad << 2);
#pragma unroll
        for (int j = 0; j < 4; j++) {
            const int c = col0 + (wn << 6) + (j << 4) + l16;
#pragma unroll
            for (int g = 0; g < 4; g++) {
                const size_t idx = (size_t)(rb + g) * DIM + c;
                dreg[i][j][g] = drive[idx];
                sreg[i][j][g] = st0[idx];
            }
        }
    }

    for (int t = 0; t < 64; ++t) {
        const signed char* Ahc = (t & 1) ? h2 : h1;
        const signed char* Alc = (t & 1) ? l2 : l1;
        signed char* Oh = (t & 1) ? h1 : h2;
        signed char* Ol = (t & 1) ? l1 : l2;

        const signed char* a_src[4];
#pragma unroll
        for (int i = 0; i < 4; i++)
            a_src[i] = (a_lo[i] ? Alc : Ahc) + a_off[i];

        i32x4 acch[2][4] = {};
        i32x4 accl[2][4] = {};

        // prologue: stage A buf0 (B buf0 was pre-staged before the barrier,
        // except at t=0 where we stage it here)
#pragma unroll
        for (int i = 0; i < 4; i++) async16(a_src[i], sA[0] + a_dst[i]);
        if (t == 0) {
#pragma unroll
            for (int i = 0; i < 4; i++) async16(b_src[i], sB[0] + b_dst[i]);
        }
        __syncthreads();
        for (int it = 0; it < 16; it++) {          // BK = 128 bytes of k
            const int p = it & 1;
            if (it + 1 < 16) {
                const int k0 = (it + 1) * 128;
#pragma unroll
                for (int i = 0; i < 4; i++) {
                    async16(a_src[i] + k0, sA[1 - p] + a_dst[i]);
                    async16(b_src[i] + k0, sB[1 - p] + b_dst[i]);
                }
            }
#pragma unroll
            for (int kk = 0; kk < 2; kk++) {       // two K=64 MFMA phases
                i32x4 ahf[2], alf[2], bvf[4];
#pragma unroll
                for (int i = 0; i < 2; i++) {
                    const int r = (wm << 5) + (i << 4) + l16;
                    const int cs = ((kk << 2) + quad) ^ (r & 7);
                    ahf[i] = *(const i32x4*)(sA[p] + ((r << 4) + cs) * 16);
                    alf[i] = *(const i32x4*)(sA[p] + ((r << 4) + 8 + cs) * 16);
                }
#pragma unroll
                for (int j = 0; j < 4; j++) {
                    const int r = (wn << 6) + (j << 4) + l16;
                    const int cs = ((kk << 2) + quad) ^ (r & 7);
                    bvf[j] = *(const i32x4*)(sB[p] + ((r << 3) + cs) * 16);
                }
#pragma unroll
                for (int i = 0; i < 2; i++)
#pragma unroll
                    for (int j = 0; j < 4; j++) {
                        acch[i][j] = __builtin_amdgcn_mfma_i32_16x16x64_i8(ahf[i], bvf[j], acch[i][j], 0, 0, 0);
                        accl[i][j] = __builtin_amdgcn_mfma_i32_16x16x64_i8(alf[i], bvf[j], accl[i][j], 0, 0, 0);
                    }
            }
            __syncthreads();
        }

        // pre-stage next step's B buf0 (state-independent; sB[0] free: last
        // read at it=14, and the it=15 __syncthreads retired all reads).
        // In-flight loads are drained by next step's prologue __syncthreads.
        if (t < 63) {
#pragma unroll
            for (int i = 0; i < 4; i++) async16(b_src[i], sB[0] + b_dst[i]);
        }

        // epilogue: all inputs in registers; write next-step i8 state
#pragma unroll
        for (int i = 0; i < 2; i++) {
            const int rb = row0 + (wm << 5) + (i << 4) + (quad << 2);
#pragma unroll
            for (int j = 0; j < 4; j++) {
                const int c = col0 + (wn << 6) + (j << 4) + l16;
#pragma unroll
                for (int g = 0; g < 4; g++) {
                    const size_t idx = (size_t)(rb + g) * DIM + c;
                    int prod = acch[i][j][g] * 128 + accl[i][j][g];   // exact int
                    float y = dreg[i][j][g] + (float)prod * (1.0f / 16384.0f);
                    float e = __expf(2.0f * y);
                    float th = 1.0f - 2.0f / (e + 1.0f);
                    float s = (1.0f - LEAK) * sreg[i][j][g] + LEAK * th;
                    sreg[i][j][g] = s;
                    if (t < 63) {
                        int q = (int)rintf(s * 16384.f);
                        q = q > 16383 ? 16383 : (q < -16383 ? -16383 : q);
                        Oh[idx] = (signed char)(q >> 7);
                        Ol[idx] = (signed char)(q & 127);
                    } else {
                        out[idx] = s;
                    }
                }
            }
        }

        if (t < 63) {
            __syncthreads();   // every wave's state stores are vmcnt-drained to L2
            if (tid == 0) {
                __threadfence();   // release: write back XCD L2 (block's stores)
                unsigned prev = __hip_atomic_fetch_add(
                    &g_barcnt, 1u, __ATOMIC_ACQ_REL, __HIP_MEMORY_SCOPE_AGENT);
                const unsigned gen = (unsigned)(t + 1);
                if (prev == gen * 512u - 1u) {
                    __hip_atomic_store(&g_barflag, gen, __ATOMIC_RELEASE,
                                       __HIP_MEMORY_SCOPE_AGENT);
                } else {
                    while (__hip_atomic_load(&g_barflag, __ATOMIC_ACQUIRE,
                                             __HIP_MEMORY_SCOPE_AGENT) < gen)
                        __builtin_amdgcn_s_sleep(8);
                }
                __threadfence();   // acquire: invalidate stale L1/L2 lines
            }
            __syncthreads();
        }
    }

    // self-clean so the next launch starts from zeroed barrier state
    if (tid == 0) {
        unsigned d = __hip_atomic_fetch_add(&g_done, 1u, __ATOMIC_ACQ_REL,
                                            __HIP_MEMORY_SCOPE_AGENT);
        if (d == 511u) {
            __hip_atomic_store(&g_barcnt, 0u, __ATOMIC_RELEASE, __HIP_MEMORY_SCOPE_AGENT);
            __hip_atomic_store(&g_barflag, 0u, __ATOMIC_RELEASE, __HIP_MEMORY_SCOPE_AGENT);
            __hip_atomic_store(&g_done, 0u, __ATOMIC_RELEASE, __HIP_MEMORY_SCOPE_AGENT);
        }
    }
}

extern "C" void kernel_launch(void* const* d_in, const int* in_sizes, int n_in,
                              void* d_out, int out_size, void* d_ws, size_t ws_size,
                              hipStream_t stream) {
    const float* x    = (const float*)d_in[0];
    const float* wgt  = (const float*)d_in[1];
    const float* adj  = (const float*)d_in[2];
    const float* bias = (const float*)d_in[3];
    const float* st0  = (const float*)d_in[4];
    float* out = (float*)d_out;

    const size_t NE = (size_t)DIM * DIM;
    // ws (52 MB): adjT_i8(4) | drive(16) | bufA..bufD bf16(32);
    // i8 state ping-pong (4x4MB) aliases bufA/bufB after drive GEMMs retire.
    signed char* adjT = (signed char*)d_ws;
    float* drive = (float*)(adjT + NE);
    unsigned short* bufA = (unsigned short*)(drive + NE);
    unsigned short* bufB = bufA + NE;
    unsigned short* bufC = bufB + NE;
    unsigned short* bufD = bufC + NE;
    signed char* h1 = (signed char*)bufA;
    signed char* l1 = h1 + NE;
    signed char* h2 = l1 + NE;
    signed char* l2 = h2 + NE;

    dim3 blk(256);
    transpose_split<<<dim3(64, 64), blk, 0, stream>>>(wgt, bufC, bufD);
    split_kernel<<<dim3(4096), blk, 0, stream>>>(x, bufA, bufB);
    transpose_i8<<<dim3(64, 64), blk, 0, stream>>>(adj, adjT);

    gemm_bf16<0><<<dim3(512), blk, 0, stream>>>(bufA, bufB, bufC, (const float*)0,
                                                (const float*)0, drive);
    gemm_bf16<1><<<dim3(512), blk, 0, stream>>>(bufA, bufB, bufD, drive, bias, drive);

    quant_split<<<dim3(4096), blk, 0, stream>>>(st0, h1, l1);

    step_persist<<<dim3(512), blk, 0, stream>>>(h1, l1, h2, l2, adjT, drive,
                                                st0, out);
}

// Round 8
// 1915.784 us; speedup vs baseline: 2.8640x; 2.8640x over previous
//
#include <hip/hip_runtime.h>

#define DIM 2048
#define LEAK 0.2f

typedef __bf16 bf16x8 __attribute__((ext_vector_type(8)));
typedef float  f32x4  __attribute__((ext_vector_type(4)));
typedef unsigned int u32x4 __attribute__((ext_vector_type(4)));
typedef int    i32x4  __attribute__((ext_vector_type(4)));

static __device__ __forceinline__ unsigned short f2bf(float f) {
    unsigned int x = __float_as_uint(f);
    return (unsigned short)((x + 0x7fffu + ((x >> 16) & 1u)) >> 16);  // RNE
}
static __device__ __forceinline__ float bf2f(unsigned short h) {
    return __uint_as_float(((unsigned int)h) << 16);
}

static __device__ __forceinline__ void async16(const void* g, void* s) {
    __builtin_amdgcn_global_load_lds(
        (const __attribute__((address_space(1))) void*)g,
        (__attribute__((address_space(3))) void*)s, 16, 0, 0);
}

static __device__ __forceinline__ bf16x8 ld_bf16_frag(const char* p) {
    union { u32x4 u; bf16x8 v; } cv;
    cv.u = *(const u32x4*)p;   // ds_read_b128
    return cv.v;
}

// ---------------- prep kernels ----------------

__global__ __launch_bounds__(256) void split_kernel(
    const float* __restrict__ in,
    unsigned short* __restrict__ hi, unsigned short* __restrict__ lo) {
    int idx = blockIdx.x * 256 + threadIdx.x;
    float4 v = ((const float4*)in)[idx];
    ushort4 h, l;
    h.x = f2bf(v.x); l.x = f2bf(v.x - bf2f(h.x));
    h.y = f2bf(v.y); l.y = f2bf(v.y - bf2f(h.y));
    h.z = f2bf(v.z); l.z = f2bf(v.z - bf2f(h.z));
    h.w = f2bf(v.w); l.w = f2bf(v.w - bf2f(h.w));
    ((ushort4*)hi)[idx] = h;
    ((ushort4*)lo)[idx] = l;
}

__global__ __launch_bounds__(256) void transpose_split(
    const float* __restrict__ in,
    unsigned short* __restrict__ hiT, unsigned short* __restrict__ loT) {
    __shared__ float t[32][33];
    int bx = blockIdx.x, by = blockIdx.y;
    int tx = threadIdx.x & 31, ty4 = (threadIdx.x >> 5) << 2;
#pragma unroll
    for (int i = 0; i < 4; i++)
        t[ty4 + i][tx] = in[(size_t)(by * 32 + ty4 + i) * DIM + bx * 32 + tx];
    __syncthreads();
#pragma unroll
    for (int i = 0; i < 4; i++) {
        float v = t[tx][ty4 + i];
        size_t o = (size_t)(bx * 32 + ty4 + i) * DIM + by * 32 + tx;
        unsigned short h = f2bf(v);
        hiT[o] = h;
        loT[o] = f2bf(v - bf2f(h));
    }
}

__global__ __launch_bounds__(256) void transpose_i8(
    const float* __restrict__ in, signed char* __restrict__ outT) {
    __shared__ float t[32][33];
    int bx = blockIdx.x, by = blockIdx.y;
    int tx = threadIdx.x & 31, ty4 = (threadIdx.x >> 5) << 2;
#pragma unroll
    for (int i = 0; i < 4; i++)
        t[ty4 + i][tx] = in[(size_t)(by * 32 + ty4 + i) * DIM + bx * 32 + tx];
    __syncthreads();
#pragma unroll
    for (int i = 0; i < 4; i++)
        outT[(size_t)(bx * 32 + ty4 + i) * DIM + by * 32 + tx] =
            (signed char)t[tx][ty4 + i];
}

__global__ __launch_bounds__(256) void quant_split(
    const float* __restrict__ in,
    signed char* __restrict__ hi, signed char* __restrict__ lo) {
    int idx = blockIdx.x * 256 + threadIdx.x;
    float4 v = ((const float4*)in)[idx];
    char4 h, l;
    {
        int q = (int)rintf(v.x * 16384.f); q = q > 16383 ? 16383 : (q < -16383 ? -16383 : q);
        h.x = (signed char)(q >> 7); l.x = (signed char)(q & 127);
    }
    {
        int q = (int)rintf(v.y * 16384.f); q = q > 16383 ? 16383 : (q < -16383 ? -16383 : q);
        h.y = (signed char)(q >> 7); l.y = (signed char)(q & 127);
    }
    {
        int q = (int)rintf(v.z * 16384.f); q = q > 16383 ? 16383 : (q < -16383 ? -16383 : q);
        h.z = (signed char)(q >> 7); l.z = (signed char)(q & 127);
    }
    {
        int q = (int)rintf(v.w * 16384.f); q = q > 16383 ? 16383 : (q < -16383 ? -16383 : q);
        h.w = (signed char)(q >> 7); l.w = (signed char)(q & 127);
    }
    ((char4*)hi)[idx] = h;
    ((char4*)lo)[idx] = l;
}

// ---------------- bf16 dual-A GEMM (drive), tile 64x128, dbuf ----------------
// MODE 0: Cout = (Ahi+Alo) @ B^T        MODE 1: Cout = Cin + P + bias[n]
// (proven round-0 kernel, 2x44us)
template <int MODE>
__global__ __launch_bounds__(256) void gemm_bf16(
    const unsigned short* __restrict__ Ahi,
    const unsigned short* __restrict__ Alo,
    const unsigned short* __restrict__ BT,
    const float* __restrict__ Cin,
    const float* __restrict__ bias,
    float* __restrict__ Cout) {
    __shared__ alignas(16) char sA[2][16384];
    __shared__ alignas(16) char sB[2][16384];

    const int bid = blockIdx.x;
    const int xcd = bid & 7, slot = bid >> 3;
    const int tm = ((xcd >> 1) << 3) + (slot >> 3);      // 0..31
    const int tn = ((xcd & 1) << 3) + (slot & 7);        // 0..15
    const int row0 = tm << 6, col0 = tn << 7;

    const int tid = threadIdx.x;
    const int lane = tid & 63;
    const int quad = lane >> 4, l16 = lane & 15;
    const int wave = tid >> 6;
    const int wm = wave >> 1, wn = wave & 1;

    const unsigned short* a_src[4]; int a_dst[4];
    const unsigned short* b_src[4]; int b_dst[4];
#pragma unroll
    for (int i = 0; i < 4; i++) {
        int s = tid + 256 * i;                 // 0..1023
        {
            int r = s >> 4, g = (s >> 3) & 1, c = (s & 7) ^ (r & 7);
            a_src[i] = (g ? Alo : Ahi) + (size_t)(row0 + r) * DIM + c * 8;
            a_dst[i] = s * 16;
        }
        {
            int r = s >> 3, c = (s & 7) ^ (r & 7);
            b_src[i] = BT + (size_t)(col0 + r) * DIM + c * 8;
            b_dst[i] = s * 16;
        }
    }

    f32x4 acc[2][4] = {};

    auto stage = [&](int p, int k0) {
#pragma unroll
        for (int i = 0; i < 4; i++) {
            async16(a_src[i] + k0, sA[p] + a_dst[i]);
            async16(b_src[i] + k0, sB[p] + b_dst[i]);
        }
    };

    stage(0, 0);
    __syncthreads();
    for (int it = 0; it < 32; it++) {          // BK = 64 elems (128B)
        const int p = it & 1;
        if (it + 1 < 32) stage(1 - p, (it + 1) * 64);
#pragma unroll
        for (int kk = 0; kk < 2; kk++) {       // two K=32 MFMA phases
            bf16x8 ah[2], al[2], bv[4];
#pragma unroll
            for (int i = 0; i < 2; i++) {
                const int r = (wm << 5) + (i << 4) + l16;
                const int cs = ((kk << 2) + quad) ^ (r & 7);
                ah[i] = ld_bf16_frag(sA[p] + ((r << 4) + cs) * 16);
                al[i] = ld_bf16_frag(sA[p] + ((r << 4) + 8 + cs) * 16);
            }
#pragma unroll
            for (int j = 0; j < 4; j++) {
                const int r = (wn << 6) + (j << 4) + l16;
                const int cs = ((kk << 2) + quad) ^ (r & 7);
                bv[j] = ld_bf16_frag(sB[p] + ((r << 3) + cs) * 16);
            }
#pragma unroll
            for (int i = 0; i < 2; i++)
#pragma unroll
                for (int j = 0; j < 4; j++) {
                    acc[i][j] = __builtin_amdgcn_mfma_f32_16x16x32_bf16(ah[i], bv[j], acc[i][j], 0, 0, 0);
                    acc[i][j] = __builtin_amdgcn_mfma_f32_16x16x32_bf16(al[i], bv[j], acc[i][j], 0, 0, 0);
                }
        }
        __syncthreads();
    }

#pragma unroll
    for (int i = 0; i < 2; i++) {
        const int rb = row0 + (wm << 5) + (i << 4) + (quad << 2);
#pragma unroll
        for (int j = 0; j < 4; j++) {
            const int c = col0 + (wn << 6) + (j << 4) + l16;
#pragma unroll
            for (int g = 0; g < 4; g++) {
                const size_t idx = (size_t)(rb + g) * DIM + c;
                if (MODE == 0) Cout[idx] = acc[i][j][g];
                else           Cout[idx] = Cin[idx] + acc[i][j][g] + bias[c];
            }
        }
    }
}

// ---------------- i8 recurrence step v8: m201-style phase schedule ----------
// 128x128 block, 512 thr = 8 waves (4 wm x 2 wn), wave tile = the r0-proven
// 32x64.  Grid 256 = exactly 1 block/CU (2 waves/SIMD -- m201's occupancy).
// LDS tri-buffer 3 x (A 32KB + B 16KB) = 144 KB; A/B layouts, swizzles, and
// fragment addressing are r0's byte-for-byte (row count 64 -> 128).
// Per K-tile t (BK = 128B), TWO dual-barrier phases:
//   B1 -> ds_read{A:8,B(j01):4} | 3 stage(t+2) -> lgkm0 -> prio1 16 MFMA prio0
//   B2 -> ds_read{B(j23):4}     | 3 stage(t+2) -> lgkm0 -> prio1 16 MFMA prio0
//   -> s_waitcnt vmcnt(6)   [certify batch t+1; batch t+2's 6 stay in flight]
// vmcnt NEVER drains to 0 in the loop (T4, m218 +38-73%); certify-then-publish
// (own vmcnt before B1) is the r2-proven race-free order.  Stage of buffer
// (t+2)%3 starts after B1 of tile t, i.e. after every wave finished reading
// that buffer in tile t-1 (its ds_reads were lgkm-drained before t-1's last
// MFMA, and arrival at B1 orders them).  setprio = T5 (active only with the
// phase role-split, m218b).
__global__ __launch_bounds__(512, 2) void step_i8(
    const signed char* __restrict__ Ah,
    const signed char* __restrict__ Al,
    const signed char* __restrict__ BT,
    const float* __restrict__ drive,
    float* __restrict__ out,
    signed char* __restrict__ Oh,
    signed char* __restrict__ Ol,
    int write_f32) {
    __shared__ alignas(16) char lds[3][49152];   // per buf: A 32KB | B 16KB

    const int bid = blockIdx.x;                  // 256 blocks = 16x16 tiles
    const int xcd = bid & 7, slot = bid >> 3;    // 8 XCDs x 32 slots
    const int tm = ((xcd >> 1) << 2) + (slot >> 3);   // 0..15
    const int tn = ((xcd & 1) << 3) + (slot & 7);     // 0..15
    const int row0 = tm << 7, col0 = tn << 7;

    const int tid = threadIdx.x;
    const int lane = tid & 63;
    const int quad = lane >> 4, l16 = lane & 15;
    const int wave = tid >> 6;        // 0..7
    const int wm = wave >> 1;         // 0..3: 32-row group
    const int wn = wave & 1;          // 0..1: 64-col group

    // staging: A 4 loads + B 2 loads per thread per K-tile (r0 mapping, 512thr)
    const signed char* a_src[4]; int a_dst[4];
    const signed char* b_src[2]; int b_dst[2];
#pragma unroll
    for (int i = 0; i < 4; i++) {
        int s = tid + 512 * i;                  // 0..2047: 128 rows x 2 pl x 8 ch
        int r = s >> 4, g = (s >> 3) & 1, c = (s & 7) ^ (r & 7);
        a_src[i] = (g ? Al : Ah) + (size_t)(row0 + r) * DIM + c * 16;
        a_dst[i] = s * 16;
    }
#pragma unroll
    for (int i = 0; i < 2; i++) {
        int s = tid + 512 * i;                  // 0..1023: 128 rows x 8 ch
        int r = s >> 3, c = (s & 7) ^ (r & 7);
        b_src[i] = BT + (size_t)(col0 + r) * DIM + c * 16;
        b_dst[i] = s * 16;
    }

    // per-lane constant read offsets (r0 fragment addressing)
    int aoff[2][2], boff[4][2];                 // [i][kk], [j][kk]
#pragma unroll
    for (int i = 0; i < 2; i++)
#pragma unroll
        for (int kk = 0; kk < 2; kk++) {
            const int r = (wm << 5) + (i << 4) + l16;
            const int cs = ((kk << 2) + quad) ^ (r & 7);
            aoff[i][kk] = ((r << 4) + cs) * 16;           // hi; lo = +128
        }
#pragma unroll
    for (int j = 0; j < 4; j++)
#pragma unroll
        for (int kk = 0; kk < 2; kk++) {
            const int r = (wn << 6) + (j << 4) + l16;
            const int cs = ((kk << 2) + quad) ^ (r & 7);
            boff[j][kk] = ((r << 3) + cs) * 16;
        }

    i32x4 acch[2][4] = {};
    i32x4 accl[2][4] = {};

    auto stage6 = [&](char* base, int k0) {     // full batch (prologue only)
#pragma unroll
        for (int i = 0; i < 4; i++) async16(a_src[i] + k0, base + a_dst[i]);
#pragma unroll
        for (int i = 0; i < 2; i++) async16(b_src[i] + k0, base + 32768 + b_dst[i]);
    };

    // prologue: batches for tiles 0 and 1 (12 loads out), certify batch 0
    stage6(lds[0], 0);
    stage6(lds[1], 128);
    asm volatile("s_waitcnt vmcnt(6)" ::: "memory");

    for (int t = 0; t < 16; ++t) {
        const char* A = lds[t % 3];
        const char* B = A + 32768;
        char* SA = lds[(t + 2) % 3];
        char* SB = SA + 32768;
        const int k2 = (t + 2) << 7;
        const bool st = (t + 2 < 16);

        __builtin_amdgcn_s_barrier();           // B1: buffer t published
        __builtin_amdgcn_sched_barrier(0);

        // ---- phase 0: reads A(all) + B(j0,j1); MFMA (i, j01) ----
        i32x4 ah[2][2], al[2][2], bv01[2][2];
#pragma unroll
        for (int i = 0; i < 2; i++)
#pragma unroll
            for (int kk = 0; kk < 2; kk++) {
                ah[i][kk] = *(const i32x4*)(A + aoff[i][kk]);
                al[i][kk] = *(const i32x4*)(A + aoff[i][kk] + 128);
            }
#pragma unroll
        for (int j = 0; j < 2; j++)
#pragma unroll
            for (int kk = 0; kk < 2; kk++)
                bv01[j][kk] = *(const i32x4*)(B + boff[j][kk]);
        if (st) {
            async16(a_src[0] + k2, SA + a_dst[0]);
            async16(a_src[1] + k2, SA + a_dst[1]);
            async16(b_src[0] + k2, SB + b_dst[0]);
        }
        asm volatile("s_waitcnt lgkmcnt(0)" ::: "memory");
        __builtin_amdgcn_sched_barrier(0);
        __builtin_amdgcn_s_setprio(1);
#pragma unroll
        for (int i = 0; i < 2; i++)
#pragma unroll
            for (int j = 0; j < 2; j++)
#pragma unroll
                for (int kk = 0; kk < 2; kk++) {
                    acch[i][j] = __builtin_amdgcn_mfma_i32_16x16x64_i8(ah[i][kk], bv01[j][kk], acch[i][j], 0, 0, 0);
                    accl[i][j] = __builtin_amdgcn_mfma_i32_16x16x64_i8(al[i][kk], bv01[j][kk], accl[i][j], 0, 0, 0);
                }
        __builtin_amdgcn_s_setprio(0);

        __builtin_amdgcn_s_barrier();           // B2: phase separator
        __builtin_amdgcn_sched_barrier(0);

        // ---- phase 1: reads B(j2,j3); MFMA (i, j23) ----
        i32x4 bv23[2][2];
#pragma unroll
        for (int j = 0; j < 2; j++)
#pragma unroll
            for (int kk = 0; kk < 2; kk++)
                bv23[j][kk] = *(const i32x4*)(B + boff[2 + j][kk]);
        if (st) {
            async16(a_src[2] + k2, SA + a_dst[2]);
            async16(a_src[3] + k2, SA + a_dst[3]);
            async16(b_src[1] + k2, SB + b_dst[1]);
        }
        asm volatile("s_waitcnt lgkmcnt(0)" ::: "memory");
        __builtin_amdgcn_sched_barrier(0);
        __builtin_amdgcn_s_setprio(1);
#pragma unroll
        for (int i = 0; i < 2; i++)
#pragma unroll
            for (int j = 0; j < 2; j++)
#pragma unroll
                for (int kk = 0; kk < 2; kk++) {
                    acch[i][2 + j] = __builtin_amdgcn_mfma_i32_16x16x64_i8(ah[i][kk], bv23[j][kk], acch[i][2 + j], 0, 0, 0);
                    accl[i][2 + j] = __builtin_amdgcn_mfma_i32_16x16x64_i8(al[i][kk], bv23[j][kk], accl[i][2 + j], 0, 0, 0);
                }
        __builtin_amdgcn_s_setprio(0);

        // certify next tile's batch; t+2's 6 loads stay in flight (never 0
        // until the staging pipeline naturally empties at t=14)
        if (t < 14) {
            asm volatile("s_waitcnt vmcnt(6)" ::: "memory");
        } else if (t == 14) {
            asm volatile("s_waitcnt vmcnt(0)" ::: "memory");
        }
    }

    // epilogue: r0-identical math
#pragma unroll
    for (int i = 0; i < 2; i++) {
        const int rb = row0 + (wm << 5) + (i << 4) + (quad << 2);
#pragma unroll
        for (int j = 0; j < 4; j++) {
            const int c = col0 + (wn << 6) + (j << 4) + l16;
#pragma unroll
            for (int g = 0; g < 4; g++) {
                const size_t idx = (size_t)(rb + g) * DIM + c;
                int prod = acch[i][j][g] * 128 + accl[i][j][g];   // exact int
                float y = drive[idx] + (float)prod * (1.0f / 16384.0f);
                float sold = (float)((int)Ah[idx] * 128 + (int)Al[idx]) * (1.0f / 16384.0f);
                float e = __expf(2.0f * y);
                float th = 1.0f - 2.0f / (e + 1.0f);
                float s = (1.0f - LEAK) * sold + LEAK * th;
                if (write_f32) out[idx] = s;
                int q = (int)rintf(s * 16384.f);
                q = q > 16383 ? 16383 : (q < -16383 ? -16383 : q);
                Oh[idx] = (signed char)(q >> 7);
                Ol[idx] = (signed char)(q & 127);
            }
        }
    }
}

extern "C" void kernel_launch(void* const* d_in, const int* in_sizes, int n_in,
                              void* d_out, int out_size, void* d_ws, size_t ws_size,
                              hipStream_t stream) {
    const float* x    = (const float*)d_in[0];
    const float* wgt  = (const float*)d_in[1];
    const float* adj  = (const float*)d_in[2];
    const float* bias = (const float*)d_in[3];
    const float* st0  = (const float*)d_in[4];
    float* out = (float*)d_out;

    const size_t NE = (size_t)DIM * DIM;
    // ws (52 MB): adjT_i8(4) | drive(16) | bufA..bufD bf16(32);
    // i8 state ping-pong (4x4MB) aliases bufA/bufB after drive GEMMs retire.
    signed char* adjT = (signed char*)d_ws;
    float* drive = (float*)(adjT + NE);
    unsigned short* bufA = (unsigned short*)(drive + NE);
    unsigned short* bufB = bufA + NE;
    unsigned short* bufC = bufB + NE;
    unsigned short* bufD = bufC + NE;
    signed char* h1 = (signed char*)bufA;
    signed char* l1 = h1 + NE;
    signed char* h2 = l1 + NE;
    signed char* l2 = h2 + NE;

    dim3 blk(256);
    transpose_split<<<dim3(64, 64), blk, 0, stream>>>(wgt, bufC, bufD);
    split_kernel<<<dim3(4096), blk, 0, stream>>>(x, bufA, bufB);
    transpose_i8<<<dim3(64, 64), blk, 0, stream>>>(adj, adjT);

    gemm_bf16<0><<<dim3(512), blk, 0, stream>>>(bufA, bufB, bufC, (const float*)0,
                                                (const float*)0, drive);
    gemm_bf16<1><<<dim3(512), blk, 0, stream>>>(bufA, bufB, bufD, drive, bias, drive);

    quant_split<<<dim3(4096), blk, 0, stream>>>(st0, h1, l1);

    signed char* hi = h1; signed char* li = l1;
    signed char* ho = h2; signed char* lo = l2;
    for (int t = 0; t < 64; t++) {
        step_i8<<<dim3(256), dim3(512), 0, stream>>>(hi, li, adjT, drive, out,
                                                     ho, lo, (t == 63) ? 1 : 0);
        signed char* th = hi; hi = ho; ho = th;
        signed char* tl = li; li = lo; lo = tl;
    }
}

// Round 9
// 1660.665 us; speedup vs baseline: 3.3040x; 1.1536x over previous
//
#include <hip/hip_runtime.h>

#define DIM 2048
#define LEAK 0.2f

typedef __bf16 bf16x8 __attribute__((ext_vector_type(8)));
typedef float  f32x4  __attribute__((ext_vector_type(4)));
typedef unsigned int u32x4 __attribute__((ext_vector_type(4)));
typedef int    i32x4  __attribute__((ext_vector_type(4)));

static __device__ __forceinline__ unsigned short f2bf(float f) {
    unsigned int x = __float_as_uint(f);
    return (unsigned short)((x + 0x7fffu + ((x >> 16) & 1u)) >> 16);  // RNE
}
static __device__ __forceinline__ float bf2f(unsigned short h) {
    return __uint_as_float(((unsigned int)h) << 16);
}

static __device__ __forceinline__ void async16(const void* g, void* s) {
    __builtin_amdgcn_global_load_lds(
        (const __attribute__((address_space(1))) void*)g,
        (__attribute__((address_space(3))) void*)s, 16, 0, 0);
}

static __device__ __forceinline__ bf16x8 ld_bf16_frag(const char* p) {
    union { u32x4 u; bf16x8 v; } cv;
    cv.u = *(const u32x4*)p;   // ds_read_b128
    return cv.v;
}

// ---------------- prep kernels ----------------

__global__ __launch_bounds__(256) void split_kernel(
    const float* __restrict__ in,
    unsigned short* __restrict__ hi, unsigned short* __restrict__ lo) {
    int idx = blockIdx.x * 256 + threadIdx.x;
    float4 v = ((const float4*)in)[idx];
    ushort4 h, l;
    h.x = f2bf(v.x); l.x = f2bf(v.x - bf2f(h.x));
    h.y = f2bf(v.y); l.y = f2bf(v.y - bf2f(h.y));
    h.z = f2bf(v.z); l.z = f2bf(v.z - bf2f(h.z));
    h.w = f2bf(v.w); l.w = f2bf(v.w - bf2f(h.w));
    ((ushort4*)hi)[idx] = h;
    ((ushort4*)lo)[idx] = l;
}

__global__ __launch_bounds__(256) void transpose_split(
    const float* __restrict__ in,
    unsigned short* __restrict__ hiT, unsigned short* __restrict__ loT) {
    __shared__ float t[32][33];
    int bx = blockIdx.x, by = blockIdx.y;
    int tx = threadIdx.x & 31, ty4 = (threadIdx.x >> 5) << 2;
#pragma unroll
    for (int i = 0; i < 4; i++)
        t[ty4 + i][tx] = in[(size_t)(by * 32 + ty4 + i) * DIM + bx * 32 + tx];
    __syncthreads();
#pragma unroll
    for (int i = 0; i < 4; i++) {
        float v = t[tx][ty4 + i];
        size_t o = (size_t)(bx * 32 + ty4 + i) * DIM + by * 32 + tx;
        unsigned short h = f2bf(v);
        hiT[o] = h;
        loT[o] = f2bf(v - bf2f(h));
    }
}

__global__ __launch_bounds__(256) void transpose_i8(
    const float* __restrict__ in, signed char* __restrict__ outT) {
    __shared__ float t[32][33];
    int bx = blockIdx.x, by = blockIdx.y;
    int tx = threadIdx.x & 31, ty4 = (threadIdx.x >> 5) << 2;
#pragma unroll
    for (int i = 0; i < 4; i++)
        t[ty4 + i][tx] = in[(size_t)(by * 32 + ty4 + i) * DIM + bx * 32 + tx];
    __syncthreads();
#pragma unroll
    for (int i = 0; i < 4; i++)
        outT[(size_t)(bx * 32 + ty4 + i) * DIM + by * 32 + tx] =
            (signed char)t[tx][ty4 + i];
}

__global__ __launch_bounds__(256) void quant_split(
    const float* __restrict__ in,
    signed char* __restrict__ hi, signed char* __restrict__ lo) {
    int idx = blockIdx.x * 256 + threadIdx.x;
    float4 v = ((const float4*)in)[idx];
    char4 h, l;
    {
        int q = (int)rintf(v.x * 16384.f); q = q > 16383 ? 16383 : (q < -16383 ? -16383 : q);
        h.x = (signed char)(q >> 7); l.x = (signed char)(q & 127);
    }
    {
        int q = (int)rintf(v.y * 16384.f); q = q > 16383 ? 16383 : (q < -16383 ? -16383 : q);
        h.y = (signed char)(q >> 7); l.y = (signed char)(q & 127);
    }
    {
        int q = (int)rintf(v.z * 16384.f); q = q > 16383 ? 16383 : (q < -16383 ? -16383 : q);
        h.z = (signed char)(q >> 7); l.z = (signed char)(q & 127);
    }
    {
        int q = (int)rintf(v.w * 16384.f); q = q > 16383 ? 16383 : (q < -16383 ? -16383 : q);
        h.w = (signed char)(q >> 7); l.w = (signed char)(q & 127);
    }
    ((char4*)hi)[idx] = h;
    ((char4*)lo)[idx] = l;
}

// ---------------- bf16 dual-A GEMM (drive) v9: 128x128, phase schedule -------
// Port of the r8-proven step_i8 structure to the drive GEMM.  128x128 block,
// 512 thr = 8 waves (4 wm x 2 wn), wave tile 32x64, grid 256 = 1 block/CU.
// LDS tri-buffer 3 x (A 32KB | B 16KB); 2-tile-deep prefetch; ONE barrier per
// K-tile; counted vmcnt(6) certify-then-publish (never 0 in-loop); compiler
// emits counted lgkmcnt for the ds_read->MFMA interleave (m97 behavior).
// Fragment byte addressing identical to the r0 gemm (bf16: c*8 elems=c*16 B).
// MODE 0: Cout = (Ahi+Alo) @ B^T        MODE 1: Cout = Cin + P + bias[n]
template <int MODE>
__global__ __launch_bounds__(512, 2) void gemm128(
    const unsigned short* __restrict__ Ahi,
    const unsigned short* __restrict__ Alo,
    const unsigned short* __restrict__ BT,
    const float* __restrict__ Cin,
    const float* __restrict__ bias,
    float* __restrict__ Cout) {
    __shared__ alignas(16) char lds[3][49152];   // per buf: A 32KB | B 16KB

    const int bid = blockIdx.x;                  // 256 blocks = 16x16 tiles
    const int xcd = bid & 7, slot = bid >> 3;
    const int tm = ((xcd >> 1) << 2) + (slot >> 3);   // 0..15
    const int tn = ((xcd & 1) << 3) + (slot & 7);     // 0..15
    const int row0 = tm << 7, col0 = tn << 7;

    const int tid = threadIdx.x;
    const int lane = tid & 63;
    const int quad = lane >> 4, l16 = lane & 15;
    const int wave = tid >> 6;
    const int wm = wave >> 1, wn = wave & 1;

    // staging: A 4 + B 2 x 16B async16 per thread per K-tile (64 bf16 of k)
    const unsigned short* a_src[4]; int a_dst[4];
    const unsigned short* b_src[2]; int b_dst[2];
#pragma unroll
    for (int i = 0; i < 4; i++) {
        int s = tid + 512 * i;                  // 0..2047: 128 rows x 2 pl x 8 ch
        int r = s >> 4, g = (s >> 3) & 1, c = (s & 7) ^ (r & 7);
        a_src[i] = (g ? Alo : Ahi) + (size_t)(row0 + r) * DIM + c * 8;
        a_dst[i] = s * 16;
    }
#pragma unroll
    for (int i = 0; i < 2; i++) {
        int s = tid + 512 * i;                  // 0..1023: 128 rows x 8 ch
        int r = s >> 3, c = (s & 7) ^ (r & 7);
        b_src[i] = BT + (size_t)(col0 + r) * DIM + c * 8;
        b_dst[i] = s * 16;
    }

    int aoff[2][2], boff[4][2];
#pragma unroll
    for (int i = 0; i < 2; i++)
#pragma unroll
        for (int kk = 0; kk < 2; kk++) {
            const int r = (wm << 5) + (i << 4) + l16;
            const int cs = ((kk << 2) + quad) ^ (r & 7);
            aoff[i][kk] = ((r << 4) + cs) * 16;           // hi; lo = +128
        }
#pragma unroll
    for (int j = 0; j < 4; j++)
#pragma unroll
        for (int kk = 0; kk < 2; kk++) {
            const int r = (wn << 6) + (j << 4) + l16;
            const int cs = ((kk << 2) + quad) ^ (r & 7);
            boff[j][kk] = ((r << 3) + cs) * 16;
        }

    f32x4 acc[2][4] = {};

    auto stage6 = [&](char* base, int k0) {      // k0 in bf16 elements
#pragma unroll
        for (int i = 0; i < 4; i++) async16(a_src[i] + k0, base + a_dst[i]);
#pragma unroll
        for (int i = 0; i < 2; i++) async16(b_src[i] + k0, base + 32768 + b_dst[i]);
    };

    stage6(lds[0], 0);
    stage6(lds[1], 64);
    asm volatile("s_waitcnt vmcnt(6)" ::: "memory");

    for (int t = 0; t < 32; ++t) {               // 32 K-tiles of 64 elems
        const char* A = lds[t % 3];
        const char* B = A + 32768;

        __builtin_amdgcn_s_barrier();            // publish buffer t
        __builtin_amdgcn_sched_barrier(0);
        if (t + 2 < 32) stage6(lds[(t + 2) % 3], (t + 2) << 6);

        bf16x8 ah[2][2], al[2][2], bv[4][2];
#pragma unroll
        for (int i = 0; i < 2; i++)
#pragma unroll
            for (int kk = 0; kk < 2; kk++) {
                ah[i][kk] = ld_bf16_frag(A + aoff[i][kk]);
                al[i][kk] = ld_bf16_frag(A + aoff[i][kk] + 128);
            }
#pragma unroll
        for (int j = 0; j < 4; j++)
#pragma unroll
            for (int kk = 0; kk < 2; kk++)
                bv[j][kk] = ld_bf16_frag(B + boff[j][kk]);

        __builtin_amdgcn_s_setprio(1);
#pragma unroll
        for (int i = 0; i < 2; i++)
#pragma unroll
            for (int j = 0; j < 4; j++)
#pragma unroll
                for (int kk = 0; kk < 2; kk++) {
                    acc[i][j] = __builtin_amdgcn_mfma_f32_16x16x32_bf16(ah[i][kk], bv[j][kk], acc[i][j], 0, 0, 0);
                    acc[i][j] = __builtin_amdgcn_mfma_f32_16x16x32_bf16(al[i][kk], bv[j][kk], acc[i][j], 0, 0, 0);
                }
        __builtin_amdgcn_s_setprio(0);

        __builtin_amdgcn_sched_barrier(0);
        if (t < 30)       asm volatile("s_waitcnt vmcnt(6)" ::: "memory");
        else if (t == 30) asm volatile("s_waitcnt vmcnt(0)" ::: "memory");
    }

#pragma unroll
    for (int i = 0; i < 2; i++) {
        const int rb = row0 + (wm << 5) + (i << 4) + (quad << 2);
#pragma unroll
        for (int j = 0; j < 4; j++) {
            const int c = col0 + (wn << 6) + (j << 4) + l16;
#pragma unroll
            for (int g = 0; g < 4; g++) {
                const size_t idx = (size_t)(rb + g) * DIM + c;
                if (MODE == 0) Cout[idx] = acc[i][j][g];
                else           Cout[idx] = Cin[idx] + acc[i][j][g] + bias[c];
            }
        }
    }
}

// ---------------- i8 recurrence step v9 ----------------
// r8-proven structure with two refinements:
//  1. ONE barrier per K-tile (the mid-tile B2 removed -- both phases read the
//     same certified buffer, no hazard) and NO explicit lgkmcnt drains: the 16
//     ds_reads and 32 MFMAs are plain C++ so the compiler emits fine-grained
//     COUNTED lgkmcnt interleave (m97 behavior; hand lgkmcnt(0) forbids it).
//  2. drive prefetched into 32 VGPRs during tile 15 (issued after the t=14
//     vmcnt(0), so staging bookkeeping is untouched) -- overlaps the 16MB
//     epilogue fetch under the last tile's MFMAs.
// vmcnt certify-then-publish identical to r8: prologue 12 out, vmcnt(6);
// per tile stage 6 for t+2 then end-of-tile vmcnt(6) certifies t+1 before the
// next barrier publishes it; never 0 until the pipeline empties (t=14).
__global__ __launch_bounds__(512, 2) void step_i8(
    const signed char* __restrict__ Ah,
    const signed char* __restrict__ Al,
    const signed char* __restrict__ BT,
    const float* __restrict__ drive,
    float* __restrict__ out,
    signed char* __restrict__ Oh,
    signed char* __restrict__ Ol,
    int write_f32) {
    __shared__ alignas(16) char lds[3][49152];   // per buf: A 32KB | B 16KB

    const int bid = blockIdx.x;                  // 256 blocks = 16x16 tiles
    const int xcd = bid & 7, slot = bid >> 3;
    const int tm = ((xcd >> 1) << 2) + (slot >> 3);   // 0..15
    const int tn = ((xcd & 1) << 3) + (slot & 7);     // 0..15
    const int row0 = tm << 7, col0 = tn << 7;

    const int tid = threadIdx.x;
    const int lane = tid & 63;
    const int quad = lane >> 4, l16 = lane & 15;
    const int wave = tid >> 6;
    const int wm = wave >> 1;         // 0..3
    const int wn = wave & 1;          // 0..1

    const signed char* a_src[4]; int a_dst[4];
    const signed char* b_src[2]; int b_dst[2];
#pragma unroll
    for (int i = 0; i < 4; i++) {
        int s = tid + 512 * i;                  // 0..2047
        int r = s >> 4, g = (s >> 3) & 1, c = (s & 7) ^ (r & 7);
        a_src[i] = (g ? Al : Ah) + (size_t)(row0 + r) * DIM + c * 16;
        a_dst[i] = s * 16;
    }
#pragma unroll
    for (int i = 0; i < 2; i++) {
        int s = tid + 512 * i;                  // 0..1023
        int r = s >> 3, c = (s & 7) ^ (r & 7);
        b_src[i] = BT + (size_t)(col0 + r) * DIM + c * 16;
        b_dst[i] = s * 16;
    }

    int aoff[2][2], boff[4][2];
#pragma unroll
    for (int i = 0; i < 2; i++)
#pragma unroll
        for (int kk = 0; kk < 2; kk++) {
            const int r = (wm << 5) + (i << 4) + l16;
            const int cs = ((kk << 2) + quad) ^ (r & 7);
            aoff[i][kk] = ((r << 4) + cs) * 16;           // hi; lo = +128
        }
#pragma unroll
    for (int j = 0; j < 4; j++)
#pragma unroll
        for (int kk = 0; kk < 2; kk++) {
            const int r = (wn << 6) + (j << 4) + l16;
            const int cs = ((kk << 2) + quad) ^ (r & 7);
            boff[j][kk] = ((r << 3) + cs) * 16;
        }

    i32x4 acch[2][4] = {};
    i32x4 accl[2][4] = {};
    float dreg[2][4][4];

    auto stage6 = [&](char* base, int k0) {
#pragma unroll
        for (int i = 0; i < 4; i++) async16(a_src[i] + k0, base + a_dst[i]);
#pragma unroll
        for (int i = 0; i < 2; i++) async16(b_src[i] + k0, base + 32768 + b_dst[i]);
    };

    stage6(lds[0], 0);
    stage6(lds[1], 128);
    asm volatile("s_waitcnt vmcnt(6)" ::: "memory");

    for (int t = 0; t < 16; ++t) {
        const char* A = lds[t % 3];
        const char* B = A + 32768;

        __builtin_amdgcn_s_barrier();            // publish buffer t
        __builtin_amdgcn_sched_barrier(0);
        if (t + 2 < 16) stage6(lds[(t + 2) % 3], (t + 2) << 7);

        if (t == 15) {
            // epilogue drive prefetch: staging drained (t=14 vmcnt(0)), so
            // these are the only outstanding VMEM ops; compiler waits before use
#pragma unroll
            for (int i = 0; i < 2; i++) {
                const int rb = row0 + (wm << 5) + (i << 4) + (quad << 2);
#pragma unroll
                for (int j = 0; j < 4; j++) {
                    const int c = col0 + (wn << 6) + (j << 4) + l16;
#pragma unroll
                    for (int g = 0; g < 4; g++)
                        dreg[i][j][g] = drive[(size_t)(rb + g) * DIM + c];
                }
            }
        }

        i32x4 ah[2][2], al[2][2], bv[4][2];
#pragma unroll
        for (int i = 0; i < 2; i++)
#pragma unroll
            for (int kk = 0; kk < 2; kk++) {
                ah[i][kk] = *(const i32x4*)(A + aoff[i][kk]);
                al[i][kk] = *(const i32x4*)(A + aoff[i][kk] + 128);
            }
#pragma unroll
        for (int j = 0; j < 4; j++)
#pragma unroll
            for (int kk = 0; kk < 2; kk++)
                bv[j][kk] = *(const i32x4*)(B + boff[j][kk]);

        __builtin_amdgcn_s_setprio(1);
#pragma unroll
        for (int i = 0; i < 2; i++)
#pragma unroll
            for (int j = 0; j < 4; j++)
#pragma unroll
                for (int kk = 0; kk < 2; kk++) {
                    acch[i][j] = __builtin_amdgcn_mfma_i32_16x16x64_i8(ah[i][kk], bv[j][kk], acch[i][j], 0, 0, 0);
                    accl[i][j] = __builtin_amdgcn_mfma_i32_16x16x64_i8(al[i][kk], bv[j][kk], accl[i][j], 0, 0, 0);
                }
        __builtin_amdgcn_s_setprio(0);

        __builtin_amdgcn_sched_barrier(0);
        if (t < 14)       asm volatile("s_waitcnt vmcnt(6)" ::: "memory");
        else if (t == 14) asm volatile("s_waitcnt vmcnt(0)" ::: "memory");
    }

    // epilogue: r0-identical math; drive from registers
#pragma unroll
    for (int i = 0; i < 2; i++) {
        const int rb = row0 + (wm << 5) + (i << 4) + (quad << 2);
#pragma unroll
        for (int j = 0; j < 4; j++) {
            const int c = col0 + (wn << 6) + (j << 4) + l16;
#pragma unroll
            for (int g = 0; g < 4; g++) {
                const size_t idx = (size_t)(rb + g) * DIM + c;
                int prod = acch[i][j][g] * 128 + accl[i][j][g];   // exact int
                float y = dreg[i][j][g] + (float)prod * (1.0f / 16384.0f);
                float sold = (float)((int)Ah[idx] * 128 + (int)Al[idx]) * (1.0f / 16384.0f);
                float e = __expf(2.0f * y);
                float th = 1.0f - 2.0f / (e + 1.0f);
                float s = (1.0f - LEAK) * sold + LEAK * th;
                if (write_f32) out[idx] = s;
                int q = (int)rintf(s * 16384.f);
                q = q > 16383 ? 16383 : (q < -16383 ? -16383 : q);
                Oh[idx] = (signed char)(q >> 7);
                Ol[idx] = (signed char)(q & 127);
            }
        }
    }
}

extern "C" void kernel_launch(void* const* d_in, const int* in_sizes, int n_in,
                              void* d_out, int out_size, void* d_ws, size_t ws_size,
                              hipStream_t stream) {
    const float* x    = (const float*)d_in[0];
    const float* wgt  = (const float*)d_in[1];
    const float* adj  = (const float*)d_in[2];
    const float* bias = (const float*)d_in[3];
    const float* st0  = (const float*)d_in[4];
    float* out = (float*)d_out;

    const size_t NE = (size_t)DIM * DIM;
    // ws (52 MB): adjT_i8(4) | drive(16) | bufA..bufD bf16(32);
    // i8 state ping-pong (4x4MB) aliases bufA/bufB after drive GEMMs retire.
    signed char* adjT = (signed char*)d_ws;
    float* drive = (float*)(adjT + NE);
    unsigned short* bufA = (unsigned short*)(drive + NE);
    unsigned short* bufB = bufA + NE;
    unsigned short* bufC = bufB + NE;
    unsigned short* bufD = bufC + NE;
    signed char* h1 = (signed char*)bufA;
    signed char* l1 = h1 + NE;
    signed char* h2 = l1 + NE;
    signed char* l2 = h2 + NE;

    dim3 blk(256);
    transpose_split<<<dim3(64, 64), blk, 0, stream>>>(wgt, bufC, bufD);
    split_kernel<<<dim3(4096), blk, 0, stream>>>(x, bufA, bufB);
    transpose_i8<<<dim3(64, 64), blk, 0, stream>>>(adj, adjT);

    gemm128<0><<<dim3(256), dim3(512), 0, stream>>>(bufA, bufB, bufC, (const float*)0,
                                                    (const float*)0, drive);
    gemm128<1><<<dim3(256), dim3(512), 0, stream>>>(bufA, bufB, bufD, drive, bias, drive);

    quant_split<<<dim3(4096), blk, 0, stream>>>(st0, h1, l1);

    signed char* hi = h1; signed char* li = l1;
    signed char* ho = h2; signed char* lo = l2;
    for (int t = 0; t < 64; t++) {
        step_i8<<<dim3(256), dim3(512), 0, stream>>>(hi, li, adjT, drive, out,
                                                     ho, lo, (t == 63) ? 1 : 0);
        signed char* th = hi; hi = ho; ho = th;
        signed char* tl = li; li = lo; lo = tl;
    }
}